// Round 22
// baseline (856.990 us; speedup 1.0000x reference)
//
#include <hip/hip_runtime.h>
#include <hip/hip_bf16.h>
#include <math.h>

#define EPSF 1e-15f

typedef __attribute__((ext_vector_type(8))) short bf16x8;
typedef __attribute__((ext_vector_type(4))) float f32x4;

__device__ __forceinline__ void gload_lds16(const void* g, void* l){
  __builtin_amdgcn_global_load_lds(
    (const __attribute__((address_space(1))) unsigned int*)(g),
    (__attribute__((address_space(3))) unsigned int*)(l), 16, 0, 0);
}

__device__ __forceinline__ float blo(unsigned v){ return __uint_as_float(v << 16); }
__device__ __forceinline__ float bhi(unsigned v){ return __uint_as_float(v & 0xFFFF0000u); }
__device__ __forceinline__ unsigned short b16(float v){
  __hip_bfloat16 b = __float2bfloat16(v);
  return *reinterpret_cast<unsigned short*>(&b);
}

// ===================== graph preprocessing =====================

__global__ void k_count_deg(const int* __restrict__ edges, int E, int* indeg, int* outdeg){
  int e = blockIdx.x*blockDim.x + threadIdx.x;
  if (e >= E) return;
  int r = edges[e], c = edges[E+e];
  atomicAdd(&outdeg[r], 1);
  atomicAdd(&indeg[c], 1);
}

__device__ __forceinline__ void scan_body(const int* cnt, int* rowptr, int* cur,
                                          float* dinvOut, int n){
  __shared__ int csum[257];
  const int T = 256;
  int chunk = (n + T - 1)/T;
  int t = threadIdx.x;
  int beg = t*chunk, end = min(n, beg + chunk);
  int s = 0;
  for (int i = beg; i < end; ++i) s += cnt[i];
  csum[t+1] = s;
  if (t == 0) csum[0] = 0;
  __syncthreads();
  if (t == 0){ for (int i = 1; i <= T; ++i) csum[i] += csum[i-1]; }
  __syncthreads();
  int acc = csum[t];
  for (int i = beg; i < end; ++i){
    rowptr[i] = acc;
    cur[i] = acc;
    if (dinvOut) dinvOut[i] = rsqrtf((float)(cnt[i] + 1));
    acc += cnt[i];
  }
  if (t == T-1) rowptr[n] = csum[T];
}

__global__ void k_scan_batch(const int* __restrict__ indeg, const int* __restrict__ outdeg,
                             int* rp_in, int* rp_out, int* cur_in, int* cur_out,
                             float* dinv, int n){
  if (blockIdx.x == 0) scan_body(indeg,  rp_in,  cur_in,  dinv,    n);
  else                 scan_body(outdeg, rp_out, cur_out, nullptr, n);
}

__global__ void k_fill_csr(const int* __restrict__ edges, int E, int* cur_in, int* cur_out,
                           int* __restrict__ src, int* __restrict__ dst){
  int e = blockIdx.x*blockDim.x + threadIdx.x;
  if (e >= E) return;
  int r = edges[e], c = edges[E+e];
  int p = atomicAdd(&cur_in[c], 1);  src[p] = r;
  int q = atomicAdd(&cur_out[r], 1); dst[q] = c;
}

// ===================== GCN aggregation: half-wave per node, uint2 gathers =====================
// 128 threads = 4 nodes; 32 lanes x uint2 (4 bf16) = 128 cols.
__global__ __launch_bounds__(128)
void k_gcn_agg_v2(const __hip_bfloat16* __restrict__ hb, const float* __restrict__ dinv,
                  const int* __restrict__ rowptr, const int* __restrict__ src,
                  const float* __restrict__ bias, float* __restrict__ outf,
                  __hip_bfloat16* __restrict__ outb, int Hd4, int N, int do_tanh){
  int c = blockIdx.x*4 + (threadIdx.x >> 5);
  if (c >= N) return;
  int lane = threadIdx.x & 31;
  const uint2* h64 = (const uint2*)hb;
  float dc = dinv[c];
  uint2 vs = h64[(size_t)c*Hd4 + lane];
  float s0 = blo(vs.x)*dc, s1 = bhi(vs.x)*dc, s2 = blo(vs.y)*dc, s3 = bhi(vs.y)*dc;
  float t0 = 0.f, t1 = 0.f, t2 = 0.f, t3 = 0.f;
  int e0 = rowptr[c], e1 = rowptr[c+1];
  int e = e0;
  for (; e + 1 < e1; e += 2){
    int sa = src[e], sb = src[e+1];
    float da = dinv[sa], db = dinv[sb];
    uint2 va = h64[(size_t)sa*Hd4 + lane];
    uint2 vb = h64[(size_t)sb*Hd4 + lane];
    s0 += blo(va.x)*da; s1 += bhi(va.x)*da; s2 += blo(va.y)*da; s3 += bhi(va.y)*da;
    t0 += blo(vb.x)*db; t1 += bhi(vb.x)*db; t2 += blo(vb.y)*db; t3 += bhi(vb.y)*db;
  }
  if (e < e1){
    int sa = src[e];
    float da = dinv[sa];
    uint2 va = h64[(size_t)sa*Hd4 + lane];
    s0 += blo(va.x)*da; s1 += bhi(va.x)*da; s2 += blo(va.y)*da; s3 += bhi(va.y)*da;
  }
  s0 += t0; s1 += t1; s2 += t2; s3 += t3;
  float4 bb = ((const float4*)bias)[lane];
  float v0 = s0*dc + bb.x;
  float v1 = s1*dc + bb.y;
  float v2 = s2*dc + bb.z;
  float v3 = s3*dc + bb.w;
  if (do_tanh){ v0 = tanhf(v0); v1 = tanhf(v1); v2 = tanhf(v2); v3 = tanhf(v3); }
  if (outf){
    float4 o; o.x = v0; o.y = v1; o.z = v2; o.w = v3;
    ((float4*)(outf + (size_t)c*(Hd4*4)))[lane] = o;
  }
  if (outb){
    uint2 r;
    r.x = ((unsigned)b16(v1) << 16) | (unsigned)b16(v0);
    r.y = ((unsigned)b16(v3) << 16) | (unsigned)b16(v2);
    ((uint2*)(outb + (size_t)c*(Hd4*4)))[lane] = r;
  }
}

// a_s[n,:] = sum over out-edges; uint2 loads (4 bf16), float4 stores
__global__ __launch_bounds__(128)
void k_as_agg_b4(const __hip_bfloat16* __restrict__ sb, const int* __restrict__ rowptr,
                 const int* __restrict__ dst, float* __restrict__ a_s,
                 int K, int K4, int KP4){
  int n = blockIdx.x;
  int e0 = rowptr[n], e1 = rowptr[n+1];
  const uint2* sb64 = (const uint2*)sb;
  for (int k = threadIdx.x; k < K4; k += blockDim.x){
    float a0 = 0.f, a1 = 0.f, a2 = 0.f, a3 = 0.f;
    for (int e = e0; e < e1; ++e){
      uint2 v = sb64[(size_t)dst[e]*KP4 + k];
      a0 += blo(v.x); a1 += bhi(v.x);
      a2 += blo(v.y); a3 += bhi(v.y);
    }
    ((f32x4*)(a_s + (size_t)n*K))[k] = (f32x4){a0, a1, a2, a3};
  }
}

// ===================== packs / transposes =====================
__global__ void k_pack_bf16pad(const float* __restrict__ x, __hip_bfloat16* __restrict__ y,
                               int rows, int K, int KP){
  long long n = (long long)rows*KP;
  for (long long i = (long long)blockIdx.x*blockDim.x + threadIdx.x; i < n;
       i += (long long)gridDim.x*blockDim.x){
    int row = (int)(i / KP), col = (int)(i - (long long)row*KP);
    y[i] = (col < K) ? __float2bfloat16(x[(size_t)row*K + col]) : __float2bfloat16(0.f);
  }
}

__global__ void k_zero_pads(__hip_bfloat16* __restrict__ s_b, __hip_bfloat16* __restrict__ u_b,
                            int N, int K, int KP, int MP){
  int padc = KP - K;
  long long nA = (long long)N*padc;
  long long nB = (long long)(MP - N)*KP;
  long long tot = 2*(nA + nB);
  __hip_bfloat16 z = __float2bfloat16(0.f);
  for (long long i = (long long)blockIdx.x*blockDim.x + threadIdx.x; i < tot;
       i += (long long)gridDim.x*blockDim.x){
    long long j = i >> 1;
    __hip_bfloat16* buf = (i & 1) ? u_b : s_b;
    if (j < nA){
      int row = (int)(j / padc), col = K + (int)(j % padc);
      buf[(size_t)row*KP + col] = z;
    } else {
      buf[(size_t)N*KP + (j - nA)] = z;
    }
  }
}

__device__ __forceinline__ void transpose_tile(const float* X, __hip_bfloat16* XT,
                                               int R, int C, int Cp, int Np,
                                               int bx, int by){
  __shared__ float t[32][33];
  int jb = bx*32;
  int ib = by*32;
  int tx = threadIdx.x & 31, ty = threadIdx.x >> 5;
  #pragma unroll
  for (int k = 0; k < 4; ++k){
    int i = ib + ty + k*8, j = jb + tx;
    t[ty + k*8][tx] = (i < R && j < C) ? X[(size_t)i*C + j] : 0.f;
  }
  __syncthreads();
  #pragma unroll
  for (int k = 0; k < 4; ++k){
    int jr = jb + ty + k*8, ic = ib + tx;
    if (jr < Cp && ic < Np)
      XT[(size_t)jr*Np + ic] = __float2bfloat16(t[tx][ty + k*8]);
  }
}

__device__ __forceinline__ void transpose_tile_b(const __hip_bfloat16* X, __hip_bfloat16* XT,
                                                 int R, int C, int Cp, int Np,
                                                 int bx, int by){
  __shared__ float tb[32][33];
  int jb = bx*32;
  int ib = by*32;
  int tx = threadIdx.x & 31, ty = threadIdx.x >> 5;
  #pragma unroll
  for (int k = 0; k < 4; ++k){
    int i = ib + ty + k*8, j = jb + tx;
    tb[ty + k*8][tx] = (i < R && j < C) ? __bfloat162float(X[(size_t)i*C + j]) : 0.f;
  }
  __syncthreads();
  #pragma unroll
  for (int k = 0; k < 4; ++k){
    int jr = jb + ty + k*8, ic = ib + tx;
    if (jr < Cp && ic < Np)
      XT[(size_t)jr*Np + ic] = __float2bfloat16(tb[tx][ty + k*8]);
  }
}

struct TPar { const float* src; __hip_bfloat16* dst; int R, C, Cp, Np; };

__global__ __launch_bounds__(256)
void k_transpose_batch6(TPar p0, TPar p1, TPar p2, TPar p3, TPar p4, TPar p5){
  TPar p;
  switch (blockIdx.z){
    case 0: p = p0; break;
    case 1: p = p1; break;
    case 2: p = p2; break;
    case 3: p = p3; break;
    case 4: p = p4; break;
    default: p = p5; break;
  }
  if ((int)blockIdx.x >= (p.Cp + 31)/32 || (int)blockIdx.y >= (p.Np + 31)/32) return;
  transpose_tile(p.src, p.dst, p.R, p.C, p.Cp, p.Np, blockIdx.x, blockIdx.y);
}

__global__ __launch_bounds__(256)
void k_transpose_batch3(const float* __restrict__ s, __hip_bfloat16* __restrict__ st,
                        const float* __restrict__ a_s, __hip_bfloat16* __restrict__ a_st,
                        const __hip_bfloat16* __restrict__ xbb, __hip_bfloat16* __restrict__ xbt,
                        int N, int K, int KP, int Hd, int NP){
  int z = blockIdx.z;
  if (z < 2){
    transpose_tile(z ? a_s : s, z ? a_st : st, N, K, KP, NP, blockIdx.x, blockIdx.y);
  } else {
    if ((int)blockIdx.x*32 >= Hd) return;
    transpose_tile_b(xbb, xbt, N, Hd, Hd, NP, blockIdx.x, blockIdx.y);
  }
}

__global__ __launch_bounds__(256)
void k_transpose_ptop(const float* __restrict__ P, __hip_bfloat16* __restrict__ Pt,
                      const float* __restrict__ op, __hip_bfloat16* __restrict__ opT,
                      int K, int KP, int Hd){
  if (blockIdx.z == 0){
    transpose_tile(P, Pt, K, K, KP, KP, blockIdx.x, blockIdx.y);
  } else {
    if ((int)blockIdx.x*32 >= Hd) return;
    transpose_tile(op, opT, K, Hd, Hd, KP, blockIdx.x, blockIdx.y);
  }
}

// ===================== MFMA bf16 GEMM (abt), KT=64 with [2][128][32] LDS subtiles =====================
#define MT 128
#define NT 128
__global__ __launch_bounds__(256)
void k_gemm_abt_mfma(const short* __restrict__ A, const short* __restrict__ B,
                     const float* __restrict__ bias,
                     float* __restrict__ Cf, __hip_bfloat16* __restrict__ Cb,
                     int M, int Nd, int KP, int ldcb, int swz){
  __shared__ __align__(16) short Asl[2*128*32];
  __shared__ __align__(16) short Bsl[2*128*32];
  int bx = blockIdx.x, by = blockIdx.y;
  if (swz){
    int gx = gridDim.x;
    int nwg = gx * gridDim.y;
    int bid = by*gx + bx;
    int q = nwg >> 3, r = nwg & 7;
    int xcd = bid & 7, o = bid >> 3;
    int nb = (xcd < r ? xcd*(q+1) : r*(q+1) + (xcd - r)*q) + o;
    bx = nb % gx; by = nb / gx;
  }
  int tid = threadIdx.x;
  int lane = tid & 63, wave = tid >> 6;
  int wr = wave >> 1, wc = wave & 1;
  int l15 = lane & 15, l4 = lane >> 4;
  int tM = by * MT, tN = bx * NT;

  f32x4 acc[4][4];
  #pragma unroll
  for (int i = 0; i < 4; ++i)
    #pragma unroll
    for (int j = 0; j < 4; ++j) acc[i][j] = (f32x4){0.f,0.f,0.f,0.f};

  // staging: srow = tid>>2 (0..63), q2 = tid&3 (16B chunk within 64B half-row)
  int srow = tid >> 2, q2 = tid & 3;
  const short* gA0 = A + (size_t)(tM + srow)*KP + q2*8;        // rows 0-63
  const short* gA1 = A + (size_t)(tM + 64 + srow)*KP + q2*8;   // rows 64-127
  const short* gB0 = B + (size_t)(tN + srow)*KP + q2*8;
  const short* gB1 = B + (size_t)(tN + 64 + srow)*KP + q2*8;
  // LDS wave-uniform bases (shorts): call pattern {0, 2048, 4096, 6144} + wave*512
  short* lA_0 = Asl + wave*512;          // ks=0, rows 0-63
  short* lA_1 = Asl + 2048 + wave*512;   // ks=0, rows 64-127
  short* lA_2 = Asl + 4096 + wave*512;   // ks=1, rows 0-63
  short* lA_3 = Asl + 6144 + wave*512;   // ks=1, rows 64-127
  short* lB_0 = Bsl + wave*512;
  short* lB_1 = Bsl + 2048 + wave*512;
  short* lB_2 = Bsl + 4096 + wave*512;
  short* lB_3 = Bsl + 6144 + wave*512;

  for (int k0 = 0; k0 < KP; k0 += 64){
    __syncthreads();
    gload_lds16(gA0 + k0,      lA_0);
    gload_lds16(gA1 + k0,      lA_1);
    gload_lds16(gA0 + k0 + 32, lA_2);
    gload_lds16(gA1 + k0 + 32, lA_3);
    gload_lds16(gB0 + k0,      lB_0);
    gload_lds16(gB1 + k0,      lB_1);
    gload_lds16(gB0 + k0 + 32, lB_2);
    gload_lds16(gB1 + k0 + 32, lB_3);
    __syncthreads();

    #pragma unroll
    for (int ks = 0; ks < 2; ++ks){
      bf16x8 af[4], bfr[4];
      #pragma unroll
      for (int mi = 0; mi < 4; ++mi)
        af[mi] = *(const bf16x8*)(Asl + ks*4096 + (wr*64 + mi*16 + l15)*32 + l4*8);
      #pragma unroll
      for (int nj = 0; nj < 4; ++nj)
        bfr[nj] = *(const bf16x8*)(Bsl + ks*4096 + (wc*64 + nj*16 + l15)*32 + l4*8);
      #pragma unroll
      for (int mi = 0; mi < 4; ++mi)
        #pragma unroll
        for (int nj = 0; nj < 4; ++nj)
          acc[mi][nj] = __builtin_amdgcn_mfma_f32_16x16x32_bf16(af[mi], bfr[nj], acc[mi][nj], 0, 0, 0);
    }
  }

  #pragma unroll
  for (int mi = 0; mi < 4; ++mi){
    #pragma unroll
    for (int r = 0; r < 4; ++r){
      int gr = tM + wr*64 + mi*16 + l4*4 + r;
      if (gr >= M) continue;
      #pragma unroll
      for (int nj = 0; nj < 4; ++nj){
        int gc = tN + wc*64 + nj*16 + l15;
        if (gc >= Nd) continue;
        float v = acc[mi][nj][r];
        if (bias) v += bias[gc];
        if (Cf) Cf[(size_t)gr*Nd + gc] = v;
        else    Cb[(size_t)gr*ldcb + gc] = __float2bfloat16(v);
      }
    }
  }
}

// merged split-K pooling GEMMs (KT=32 layout): z/8 selects {0: s^T xb, 1: s^T a_s, 2: s^T s}
#define KT 32
__global__ __launch_bounds__(256)
void k_pool_sk(const short* __restrict__ st, const short* __restrict__ xbt,
               const short* __restrict__ a_st,
               float* __restrict__ out_pool, float* __restrict__ P, float* __restrict__ ssm,
               int K, int Hd, int KL, int kChunk){
  __shared__ __align__(16) short Asl[128*32];
  __shared__ __align__(16) short Bsl[128*32];
  int sel = blockIdx.z >> 3;
  int chunk = blockIdx.z & 7;
  const short* B = (sel == 0) ? xbt : (sel == 1) ? a_st : st;
  float* C = (sel == 0) ? out_pool : (sel == 1) ? P : ssm;
  int Nd = (sel == 0) ? Hd : K;
  if ((int)blockIdx.x * NT >= ((sel == 0) ? Hd : 512)) return;
  int tid = threadIdx.x;
  int lane = tid & 63, wave = tid >> 6;
  int wr = wave >> 1, wc = wave & 1;
  int l15 = lane & 15, l4 = lane >> 4;
  int tM = blockIdx.y * MT, tN = blockIdx.x * NT;
  int kBeg = chunk * kChunk;
  int kEnd = min(KL, kBeg + kChunk);

  f32x4 acc[4][4];
  #pragma unroll
  for (int i = 0; i < 4; ++i)
    #pragma unroll
    for (int j = 0; j < 4; ++j) acc[i][j] = (f32x4){0.f,0.f,0.f,0.f};

  const short* gA0 = st + (size_t)(tM + (tid>>2))*KL + (tid&3)*8;
  const short* gA1 = st + (size_t)(tM + 64 + (tid>>2))*KL + (tid&3)*8;
  const short* gB0 = B + (size_t)(tN + (tid>>2))*KL + (tid&3)*8;
  const short* gB1 = B + (size_t)(tN + 64 + (tid>>2))*KL + (tid&3)*8;
  short* lA0 = Asl + wave*512;
  short* lA1 = Asl + 2048 + wave*512;
  short* lB0 = Bsl + wave*512;
  short* lB1 = Bsl + 2048 + wave*512;

  for (int k0 = kBeg; k0 < kEnd; k0 += KT){
    __syncthreads();
    gload_lds16(gA0 + k0, lA0);
    gload_lds16(gA1 + k0, lA1);
    gload_lds16(gB0 + k0, lB0);
    gload_lds16(gB1 + k0, lB1);
    __syncthreads();

    bf16x8 af[4], bfr[4];
    #pragma unroll
    for (int mi = 0; mi < 4; ++mi)
      af[mi] = *(const bf16x8*)(Asl + (wr*64 + mi*16 + l15)*32 + l4*8);
    #pragma unroll
    for (int nj = 0; nj < 4; ++nj)
      bfr[nj] = *(const bf16x8*)(Bsl + (wc*64 + nj*16 + l15)*32 + l4*8);
    #pragma unroll
    for (int mi = 0; mi < 4; ++mi)
      #pragma unroll
      for (int nj = 0; nj < 4; ++nj)
        acc[mi][nj] = __builtin_amdgcn_mfma_f32_16x16x32_bf16(af[mi], bfr[nj], acc[mi][nj], 0, 0, 0);
  }

  #pragma unroll
  for (int mi = 0; mi < 4; ++mi){
    #pragma unroll
    for (int r = 0; r < 4; ++r){
      int gr = tM + wr*64 + mi*16 + l4*4 + r;
      if (gr >= K) continue;
      #pragma unroll
      for (int nj = 0; nj < 4; ++nj){
        int gc = tN + wc*64 + nj*16 + l15;
        if (gc >= Nd) continue;
        atomicAdd(&C[(size_t)gr*Nd + gc], acc[mi][nj][r]);
      }
    }
  }
}

// ===================== softmax + reductions =====================

__global__ __launch_bounds__(256)
void k_softmax(float* __restrict__ s, __hip_bfloat16* __restrict__ sb,
               const int* __restrict__ outdeg,
               float* __restrict__ scalars, int N, int K, int KP){
  int wid = threadIdx.x >> 6, lane = threadIdx.x & 63;
  int row = blockIdx.x*4 + wid;
  if (row >= N) return;
  float* sr = s + (size_t)row*K;
  __hip_bfloat16* sbr = sb + (size_t)row*KP;
  float v[8];
  float m = -INFINITY;
  #pragma unroll
  for (int i = 0; i < 8; ++i){
    int k = lane + i*64;
    v[i] = (k < K) ? sr[k] : -INFINITY;
    m = fmaxf(m, v[i]);
  }
  for (int off = 32; off; off >>= 1) m = fmaxf(m, __shfl_xor(m, off));
  float sum = 0.f;
  #pragma unroll
  for (int i = 0; i < 8; ++i){
    int k = lane + i*64;
    if (k < K){ v[i] = expf(v[i] - m); sum += v[i]; } else v[i] = 0.f;
  }
  for (int off = 32; off; off >>= 1) sum += __shfl_xor(sum, off);
  float inv = 1.f / sum;
  float ssq = 0.f;
  #pragma unroll
  for (int i = 0; i < 8; ++i){
    int k = lane + i*64;
    if (k < K){
      float p = v[i]*inv;
      sr[k] = p;
      sbr[k] = __float2bfloat16(p);
      ssq += p*p;
    }
  }
  for (int off = 32; off; off >>= 1) ssq += __shfl_xor(ssq, off);
  if (lane == 0) atomicAdd(&scalars[1], (float)outdeg[row] * ssq);
}

__global__ void k_stats1(const float* __restrict__ P, const float* __restrict__ ssm,
                         float* __restrict__ scalars, int K){
  float tr = 0.f, sq = 0.f;
  int n = K*K;
  for (int idx = blockIdx.x*blockDim.x + threadIdx.x; idx < n; idx += gridDim.x*blockDim.x){
    float v = ssm[idx]; sq += v*v;
    int i = idx / K, j = idx - i*K;
    if (i == j) tr += P[idx];
  }
  for (int off = 32; off; off >>= 1){
    tr += __shfl_xor(tr, off);
    sq += __shfl_xor(sq, off);
  }
  if ((threadIdx.x & 63) == 0){
    if (tr != 0.f) atomicAdd(&scalars[0], tr);
    atomicAdd(&scalars[2], sq);
  }
}

__global__ __launch_bounds__(256)
void k_rowsum_d(const float* __restrict__ P, float* __restrict__ dvec, int K){
  int wid = threadIdx.x >> 6, lane = threadIdx.x & 63;
  int row = blockIdx.x*4 + wid;
  if (row >= K) return;
  const float* pr = P + (size_t)row*K;
  float rs = 0.f;
  for (int j = lane; j < K; j += 64) if (j != row) rs += pr[j];
  for (int off = 32; off; off >>= 1) rs += __shfl_xor(rs, off);
  if (lane == 0) dvec[row] = sqrtf(rs) + EPSF;
}

__global__ void k_stats2(float* __restrict__ P, const float* __restrict__ ssm,
                         const float* __restrict__ dvec,
                         const float* __restrict__ scalars, float* __restrict__ out3, int K){
  float inv = 1.f / (sqrtf(scalars[2]) + EPSF);
  float isk = rsqrtf((float)K);
  float a = 0.f;
  int n = K*K;
  for (int idx = blockIdx.x*blockDim.x + threadIdx.x; idx < n; idx += gridDim.x*blockDim.x){
    int i = idx / K, j = idx - i*K;
    float v = ssm[idx]*inv - ((i == j) ? isk : 0.f);
    a += v*v;
    float pv = P[idx];
    P[idx] = (i == j) ? 0.f : pv / (dvec[i]*dvec[j]);
  }
  for (int off = 32; off; off >>= 1) a += __shfl_xor(a, off);
  if ((threadIdx.x & 63) == 0) atomicAdd(out3, a);
}

__global__ void k_finalize(const float* __restrict__ scalars, float* __restrict__ out2){
  if (threadIdx.x == 0){
    out2[0] = -(scalars[0] / (scalars[1] + EPSF));
    out2[1] = sqrtf(scalars[3]);
  }
}

// ===================== host-side orchestration =====================

extern "C" void kernel_launch(void* const* d_in, const int* in_sizes, int n_in,
                              void* d_out, int out_size, void* d_ws, size_t ws_size,
                              hipStream_t stream) {
  const float* nodes = (const float*)d_in[0];
  const int*   edges = (const int*)d_in[1];
  const float* W1 = (const float*)d_in[3];  const float* b1 = (const float*)d_in[4];
  const float* W2 = (const float*)d_in[5];  const float* b2 = (const float*)d_in[6];
  const float* pW = (const float*)d_in[7];  const float* pB = (const float*)d_in[8];
  const float* W3 = (const float*)d_in[9];  const float* b3 = (const float*)d_in[10];
  const float* W4 = (const float*)d_in[11]; const float* b4 = (const float*)d_in[12];
  const float* W5 = (const float*)d_in[13]; const float* b5 = (const float*)d_in[14];

  const int H = 128, F = 128, N = 10000, E = 320000, K = 500;
  const int KP = 512;
  const int NP = 10016;
  const int MP = 79*128;
  (void)n_in; (void)out_size; (void)in_sizes;

  float* out_x   = (float*)d_out;
  float* out_adj = out_x + (size_t)N*F;
  float* out_ls  = out_adj + (size_t)N*N;

  char* ws = (char*)d_ws;
  size_t off = 0;
  auto alloc = [&](size_t bytes) -> void* {
    off = (off + 255) & ~(size_t)255;
    void* p = ws + off;
    off += bytes;
    return p;
  };
  int*   deg2       = (int*)alloc((size_t)2*N*4);
  int*   indeg      = deg2;
  int*   outdeg     = deg2 + N;
  float* zf         = (float*)alloc(((size_t)K*H + 2*(size_t)K*K + 64)*4);
  float* out_pool   = zf;
  float* P          = zf + (size_t)K*H;
  float* ssm        = P + (size_t)K*K;
  float* scalars    = ssm + (size_t)K*K;
  __hip_bfloat16* s_b = (__hip_bfloat16*)alloc((size_t)MP*KP*2);
  __hip_bfloat16* u_b = (__hip_bfloat16*)alloc((size_t)MP*KP*2);
  int*   rowptr_in  = (int*)alloc((size_t)(N+1)*4);
  int*   rowptr_out = (int*)alloc((size_t)(N+1)*4);
  int*   cur_in     = (int*)alloc((size_t)N*4);
  int*   cur_out    = (int*)alloc((size_t)N*4);
  int*   csr_src    = (int*)alloc((size_t)E*4);
  int*   csr_dst    = (int*)alloc((size_t)E*4);
  float* dinv       = (float*)alloc((size_t)N*4);
  __hip_bfloat16* h_b  = (__hip_bfloat16*)alloc((size_t)N*H*2 + 32768);
  __hip_bfloat16* nodes_b = (__hip_bfloat16*)alloc((size_t)MP*H*2);
  __hip_bfloat16* xa_b = (__hip_bfloat16*)alloc((size_t)MP*H*2);
  __hip_bfloat16* xb_b = (__hip_bfloat16*)alloc((size_t)MP*H*2);
  float* s          = (float*)alloc((size_t)N*K*4);
  float* a_s        = (float*)alloc((size_t)N*K*4);
  float* dvec       = (float*)alloc((size_t)K*4);
  __hip_bfloat16* Pt_b = (__hip_bfloat16*)alloc((size_t)KP*KP*2);
  __hip_bfloat16* st_b = (__hip_bfloat16*)alloc((size_t)KP*NP*2);
  __hip_bfloat16* a_st = (__hip_bfloat16*)alloc((size_t)KP*NP*2);
  __hip_bfloat16* xbt  = (__hip_bfloat16*)alloc((size_t)H*NP*2);
  __hip_bfloat16* opT  = (__hip_bfloat16*)alloc((size_t)H*KP*2);
  __hip_bfloat16* W1t  = (__hip_bfloat16*)alloc((size_t)H*F*2);
  __hip_bfloat16* W2t  = (__hip_bfloat16*)alloc((size_t)H*H*2);
  __hip_bfloat16* W3t  = (__hip_bfloat16*)alloc((size_t)H*H*2);
  __hip_bfloat16* W4t  = (__hip_bfloat16*)alloc((size_t)H*H*2);
  __hip_bfloat16* W5t  = (__hip_bfloat16*)alloc((size_t)F*H*2);
  __hip_bfloat16* pWt  = (__hip_bfloat16*)alloc((size_t)KP*H*2);
  (void)ws_size;

  hipMemsetAsync(deg2, 0, (size_t)2*N*4, stream);
  hipMemsetAsync(zf,   0, ((size_t)K*H + 2*(size_t)K*K + 64)*4, stream);
  k_zero_pads<<<512, 256, 0, stream>>>(s_b, u_b, N, K, KP, MP);

  // --- graph structure ---
  int eb = (E + 255)/256;
  k_count_deg<<<eb, 256, 0, stream>>>(edges, E, indeg, outdeg);
  k_scan_batch<<<2, 256, 0, stream>>>(indeg, outdeg, rowptr_in, rowptr_out,
                                      cur_in, cur_out, dinv, N);
  k_fill_csr<<<eb, 256, 0, stream>>>(edges, E, cur_in, cur_out, csr_src, csr_dst);

  // --- weight packs ---
  {
    TPar p0 = { W1, W1t, F, H, H, F };
    TPar p1 = { W2, W2t, H, H, H, H };
    TPar p2 = { W3, W3t, H, H, H, H };
    TPar p3 = { W4, W4t, H, H, H, H };
    TPar p4 = { W5, W5t, H, F, F, H };
    TPar p5 = { pW, pWt, H, K, KP, H };
    dim3 g(16, 4, 6);
    k_transpose_batch6<<<g, 256, 0, stream>>>(p0, p1, p2, p3, p4, p5);
  }
  k_pack_bf16pad<<<1024, 256, 0, stream>>>(nodes, nodes_b, N, F, F);

  auto mfma = [&](const __hip_bfloat16* A, const __hip_bfloat16* B, const float* bias,
                  float* Cf, __hip_bfloat16* Cb, int M, int Nd, int Kp, int ldcb, int swz){
    dim3 g((Nd + NT - 1)/NT, (M + MT - 1)/MT);
    k_gemm_abt_mfma<<<g, 256, 0, stream>>>((const short*)A, (const short*)B, bias,
                                           Cf, Cb, M, Nd, Kp, ldcb, swz);
  };

  // --- conv1, conv2 ---
  mfma(nodes_b, W1t, nullptr, nullptr, h_b, N, H, F, H, 0);
  k_gcn_agg_v2<<<(N+3)/4, 128, 0, stream>>>(h_b, dinv, rowptr_in, csr_src, b1, nullptr, xa_b, H/4, N, 1);
  mfma(xa_b, W2t, nullptr, nullptr, h_b, N, H, H, H, 0);
  k_gcn_agg_v2<<<(N+3)/4, 128, 0, stream>>>(h_b, dinv, rowptr_in, csr_src, b2, nullptr, xb_b, H/4, N, 1);

  // --- pooling ---
  mfma(xb_b, pWt, pB, s, nullptr, N, K, H, 0, 0);
  k_softmax<<<(N+3)/4, 256, 0, stream>>>(s, s_b, outdeg, scalars, N, K, KP);
  k_as_agg_b4<<<N, 128, 0, stream>>>(s_b, rowptr_out, csr_dst, a_s, K, K/4, KP/4);
  { dim3 g(KP/32, NP/32, 3); k_transpose_batch3<<<g, 256, 0, stream>>>(s, st_b, a_s, a_st,
                                                                       xb_b, xbt, N, K, KP, H, NP); }
  const int kChunk = 1280;
  { dim3 g(4, 4, 24); k_pool_sk<<<g, 256, 0, stream>>>((const short*)st_b, (const short*)xbt,
                                                       (const short*)a_st,
                                                       out_pool, P, ssm, K, H, NP, kChunk); }
  k_stats1<<<128, 256, 0, stream>>>(P, ssm, scalars, K);
  k_rowsum_d<<<(K+3)/4, 256, 0, stream>>>(P, dvec, K);
  k_stats2<<<128, 256, 0, stream>>>(P, ssm, dvec, scalars, &scalars[3], K);
  k_finalize<<<1, 64, 0, stream>>>(scalars, out_ls);

  // --- reconstruction ---
  { dim3 g(16, 16, 2); k_transpose_ptop<<<g, 256, 0, stream>>>(P, Pt_b, out_pool, opT, K, KP, H); }
  mfma(s_b, Pt_b, nullptr, nullptr, u_b, N, K, KP, KP, 0);
  mfma(u_b, s_b, nullptr, out_adj, nullptr, N, N, KP, 0, 1);
  mfma(s_b, opT, nullptr, nullptr, xa_b, N, H, KP, H, 0);

  // --- conv3, conv4, conv5 ---
  mfma(xa_b, W3t, nullptr, nullptr, h_b, N, H, H, H, 0);
  k_gcn_agg_v2<<<(N+3)/4, 128, 0, stream>>>(h_b, dinv, rowptr_in, csr_src, b3, nullptr, xb_b, H/4, N, 1);
  mfma(xb_b, W4t, nullptr, nullptr, h_b, N, H, H, H, 0);
  k_gcn_agg_v2<<<(N+3)/4, 128, 0, stream>>>(h_b, dinv, rowptr_in, csr_src, b4, nullptr, xa_b, H/4, N, 1);
  mfma(xa_b, W5t, nullptr, nullptr, h_b, N, F, H, F, 0);
  k_gcn_agg_v2<<<(N+3)/4, 128, 0, stream>>>(h_b, dinv, rowptr_in, csr_src, b5, out_x, nullptr, F/4, N, 0);
}

// Round 23
// 823.019 us; speedup vs baseline: 1.0413x; 1.0413x over previous
//
#include <hip/hip_runtime.h>
#include <hip/hip_bf16.h>
#include <math.h>

#define EPSF 1e-15f

typedef __attribute__((ext_vector_type(8))) short bf16x8;
typedef __attribute__((ext_vector_type(4))) float f32x4;

__device__ __forceinline__ void gload_lds16(const void* g, void* l){
  __builtin_amdgcn_global_load_lds(
    (const __attribute__((address_space(1))) unsigned int*)(g),
    (__attribute__((address_space(3))) unsigned int*)(l), 16, 0, 0);
}

__device__ __forceinline__ float blo(unsigned v){ return __uint_as_float(v << 16); }
__device__ __forceinline__ float bhi(unsigned v){ return __uint_as_float(v & 0xFFFF0000u); }
__device__ __forceinline__ unsigned short b16(float v){
  __hip_bfloat16 b = __float2bfloat16(v);
  return *reinterpret_cast<unsigned short*>(&b);
}

// ===================== graph preprocessing =====================

__global__ void k_count_deg(const int* __restrict__ edges, int E, int* indeg, int* outdeg){
  int e = blockIdx.x*blockDim.x + threadIdx.x;
  if (e >= E) return;
  int r = edges[e], c = edges[E+e];
  atomicAdd(&outdeg[r], 1);
  atomicAdd(&indeg[c], 1);
}

__device__ __forceinline__ void scan_body(const int* cnt, int* rowptr, int* cur,
                                          float* dinvOut, int n){
  __shared__ int csum[257];
  const int T = 256;
  int chunk = (n + T - 1)/T;
  int t = threadIdx.x;
  int beg = t*chunk, end = min(n, beg + chunk);
  int s = 0;
  for (int i = beg; i < end; ++i) s += cnt[i];
  csum[t+1] = s;
  if (t == 0) csum[0] = 0;
  __syncthreads();
  if (t == 0){ for (int i = 1; i <= T; ++i) csum[i] += csum[i-1]; }
  __syncthreads();
  int acc = csum[t];
  for (int i = beg; i < end; ++i){
    rowptr[i] = acc;
    cur[i] = acc;
    if (dinvOut) dinvOut[i] = rsqrtf((float)(cnt[i] + 1));
    acc += cnt[i];
  }
  if (t == T-1) rowptr[n] = csum[T];
}

__global__ void k_scan_batch(const int* __restrict__ indeg, const int* __restrict__ outdeg,
                             int* rp_in, int* rp_out, int* cur_in, int* cur_out,
                             float* dinv, int n){
  if (blockIdx.x == 0) scan_body(indeg,  rp_in,  cur_in,  dinv,    n);
  else                 scan_body(outdeg, rp_out, cur_out, nullptr, n);
}

__global__ void k_fill_csr(const int* __restrict__ edges, int E, int* cur_in, int* cur_out,
                           int* __restrict__ src, int* __restrict__ dst){
  int e = blockIdx.x*blockDim.x + threadIdx.x;
  if (e >= E) return;
  int r = edges[e], c = edges[E+e];
  int p = atomicAdd(&cur_in[c], 1);  src[p] = r;
  int q = atomicAdd(&cur_out[r], 1); dst[q] = c;
}

// ===================== GCN aggregation: half-wave per node, uint2 gathers =====================
__global__ __launch_bounds__(128)
void k_gcn_agg_v2(const __hip_bfloat16* __restrict__ hb, const float* __restrict__ dinv,
                  const int* __restrict__ rowptr, const int* __restrict__ src,
                  const float* __restrict__ bias, float* __restrict__ outf,
                  __hip_bfloat16* __restrict__ outb, int Hd4, int N, int do_tanh){
  int c = blockIdx.x*4 + (threadIdx.x >> 5);
  if (c >= N) return;
  int lane = threadIdx.x & 31;
  const uint2* h64 = (const uint2*)hb;
  float dc = dinv[c];
  uint2 vs = h64[(size_t)c*Hd4 + lane];
  float s0 = blo(vs.x)*dc, s1 = bhi(vs.x)*dc, s2 = blo(vs.y)*dc, s3 = bhi(vs.y)*dc;
  float t0 = 0.f, t1 = 0.f, t2 = 0.f, t3 = 0.f;
  int e0 = rowptr[c], e1 = rowptr[c+1];
  int e = e0;
  for (; e + 1 < e1; e += 2){
    int sa = src[e], sb = src[e+1];
    float da = dinv[sa], db = dinv[sb];
    uint2 va = h64[(size_t)sa*Hd4 + lane];
    uint2 vb = h64[(size_t)sb*Hd4 + lane];
    s0 += blo(va.x)*da; s1 += bhi(va.x)*da; s2 += blo(va.y)*da; s3 += bhi(va.y)*da;
    t0 += blo(vb.x)*db; t1 += bhi(vb.x)*db; t2 += blo(vb.y)*db; t3 += bhi(vb.y)*db;
  }
  if (e < e1){
    int sa = src[e];
    float da = dinv[sa];
    uint2 va = h64[(size_t)sa*Hd4 + lane];
    s0 += blo(va.x)*da; s1 += bhi(va.x)*da; s2 += blo(va.y)*da; s3 += bhi(va.y)*da;
  }
  s0 += t0; s1 += t1; s2 += t2; s3 += t3;
  float4 bb = ((const float4*)bias)[lane];
  float v0 = s0*dc + bb.x;
  float v1 = s1*dc + bb.y;
  float v2 = s2*dc + bb.z;
  float v3 = s3*dc + bb.w;
  if (do_tanh){ v0 = tanhf(v0); v1 = tanhf(v1); v2 = tanhf(v2); v3 = tanhf(v3); }
  if (outf){
    float4 o; o.x = v0; o.y = v1; o.z = v2; o.w = v3;
    ((float4*)(outf + (size_t)c*(Hd4*4)))[lane] = o;
  }
  if (outb){
    uint2 r;
    r.x = ((unsigned)b16(v1) << 16) | (unsigned)b16(v0);
    r.y = ((unsigned)b16(v3) << 16) | (unsigned)b16(v2);
    ((uint2*)(outb + (size_t)c*(Hd4*4)))[lane] = r;
  }
}

__global__ __launch_bounds__(128)
void k_as_agg_b4(const __hip_bfloat16* __restrict__ sb, const int* __restrict__ rowptr,
                 const int* __restrict__ dst, float* __restrict__ a_s,
                 int K, int K4, int KP4){
  int n = blockIdx.x;
  int e0 = rowptr[n], e1 = rowptr[n+1];
  const uint2* sb64 = (const uint2*)sb;
  for (int k = threadIdx.x; k < K4; k += blockDim.x){
    float a0 = 0.f, a1 = 0.f, a2 = 0.f, a3 = 0.f;
    for (int e = e0; e < e1; ++e){
      uint2 v = sb64[(size_t)dst[e]*KP4 + k];
      a0 += blo(v.x); a1 += bhi(v.x);
      a2 += blo(v.y); a3 += bhi(v.y);
    }
    ((f32x4*)(a_s + (size_t)n*K))[k] = (f32x4){a0, a1, a2, a3};
  }
}

// ===================== packs / transposes =====================
__global__ void k_pack_bf16pad(const float* __restrict__ x, __hip_bfloat16* __restrict__ y,
                               int rows, int K, int KP){
  long long n = (long long)rows*KP;
  for (long long i = (long long)blockIdx.x*blockDim.x + threadIdx.x; i < n;
       i += (long long)gridDim.x*blockDim.x){
    int row = (int)(i / KP), col = (int)(i - (long long)row*KP);
    y[i] = (col < K) ? __float2bfloat16(x[(size_t)row*K + col]) : __float2bfloat16(0.f);
  }
}

__global__ void k_zero_pads(__hip_bfloat16* __restrict__ s_b, __hip_bfloat16* __restrict__ u_b,
                            int N, int K, int KP, int MP){
  int padc = KP - K;
  long long nA = (long long)N*padc;
  long long nB = (long long)(MP - N)*KP;
  long long tot = 2*(nA + nB);
  __hip_bfloat16 z = __float2bfloat16(0.f);
  for (long long i = (long long)blockIdx.x*blockDim.x + threadIdx.x; i < tot;
       i += (long long)gridDim.x*blockDim.x){
    long long j = i >> 1;
    __hip_bfloat16* buf = (i & 1) ? u_b : s_b;
    if (j < nA){
      int row = (int)(j / padc), col = K + (int)(j % padc);
      buf[(size_t)row*KP + col] = z;
    } else {
      buf[(size_t)N*KP + (j - nA)] = z;
    }
  }
}

__device__ __forceinline__ void transpose_tile(const float* X, __hip_bfloat16* XT,
                                               int R, int C, int Cp, int Np,
                                               int bx, int by){
  __shared__ float t[32][33];
  int jb = bx*32;
  int ib = by*32;
  int tx = threadIdx.x & 31, ty = threadIdx.x >> 5;
  #pragma unroll
  for (int k = 0; k < 4; ++k){
    int i = ib + ty + k*8, j = jb + tx;
    t[ty + k*8][tx] = (i < R && j < C) ? X[(size_t)i*C + j] : 0.f;
  }
  __syncthreads();
  #pragma unroll
  for (int k = 0; k < 4; ++k){
    int jr = jb + ty + k*8, ic = ib + tx;
    if (jr < Cp && ic < Np)
      XT[(size_t)jr*Np + ic] = __float2bfloat16(t[tx][ty + k*8]);
  }
}

__device__ __forceinline__ void transpose_tile_b(const __hip_bfloat16* X, __hip_bfloat16* XT,
                                                 int R, int C, int Cp, int Np,
                                                 int bx, int by){
  __shared__ float tb[32][33];
  int jb = bx*32;
  int ib = by*32;
  int tx = threadIdx.x & 31, ty = threadIdx.x >> 5;
  #pragma unroll
  for (int k = 0; k < 4; ++k){
    int i = ib + ty + k*8, j = jb + tx;
    tb[ty + k*8][tx] = (i < R && j < C) ? __bfloat162float(X[(size_t)i*C + j]) : 0.f;
  }
  __syncthreads();
  #pragma unroll
  for (int k = 0; k < 4; ++k){
    int jr = jb + ty + k*8, ic = ib + tx;
    if (jr < Cp && ic < Np)
      XT[(size_t)jr*Np + ic] = __float2bfloat16(tb[tx][ty + k*8]);
  }
}

struct TPar { const float* src; __hip_bfloat16* dst; int R, C, Cp, Np; };

__global__ __launch_bounds__(256)
void k_transpose_batch6(TPar p0, TPar p1, TPar p2, TPar p3, TPar p4, TPar p5){
  TPar p;
  switch (blockIdx.z){
    case 0: p = p0; break;
    case 1: p = p1; break;
    case 2: p = p2; break;
    case 3: p = p3; break;
    case 4: p = p4; break;
    default: p = p5; break;
  }
  if ((int)blockIdx.x >= (p.Cp + 31)/32 || (int)blockIdx.y >= (p.Np + 31)/32) return;
  transpose_tile(p.src, p.dst, p.R, p.C, p.Cp, p.Np, blockIdx.x, blockIdx.y);
}

__global__ __launch_bounds__(256)
void k_transpose_batch3(const float* __restrict__ s, __hip_bfloat16* __restrict__ st,
                        const float* __restrict__ a_s, __hip_bfloat16* __restrict__ a_st,
                        const __hip_bfloat16* __restrict__ xbb, __hip_bfloat16* __restrict__ xbt,
                        int N, int K, int KP, int Hd, int NP){
  int z = blockIdx.z;
  if (z < 2){
    transpose_tile(z ? a_s : s, z ? a_st : st, N, K, KP, NP, blockIdx.x, blockIdx.y);
  } else {
    if ((int)blockIdx.x*32 >= Hd) return;
    transpose_tile_b(xbb, xbt, N, Hd, Hd, NP, blockIdx.x, blockIdx.y);
  }
}

__global__ __launch_bounds__(256)
void k_transpose_ptop(const float* __restrict__ P, __hip_bfloat16* __restrict__ Pt,
                      const float* __restrict__ op, __hip_bfloat16* __restrict__ opT,
                      int K, int KP, int Hd){
  if (blockIdx.z == 0){
    transpose_tile(P, Pt, K, K, KP, KP, blockIdx.x, blockIdx.y);
  } else {
    if ((int)blockIdx.x*32 >= Hd) return;
    transpose_tile(op, opT, K, Hd, Hd, KP, blockIdx.x, blockIdx.y);
  }
}

// ===================== MFMA bf16 GEMM (abt), 128x128 tile, KT=32 (proven) =====================
#define MT 128
#define NT 128
#define KT 32
__global__ __launch_bounds__(256)
void k_gemm_abt_mfma(const short* __restrict__ A, const short* __restrict__ B,
                     const float* __restrict__ bias,
                     float* __restrict__ Cf, __hip_bfloat16* __restrict__ Cb,
                     int M, int Nd, int KP, int ldcb){
  __shared__ __align__(16) short Asl[128*32];
  __shared__ __align__(16) short Bsl[128*32];
  int bx = blockIdx.x, by = blockIdx.y;
  int tid = threadIdx.x;
  int lane = tid & 63, wave = tid >> 6;
  int wr = wave >> 1, wc = wave & 1;
  int l15 = lane & 15, l4 = lane >> 4;
  int tM = by * MT, tN = bx * NT;

  f32x4 acc[4][4];
  #pragma unroll
  for (int i = 0; i < 4; ++i)
    #pragma unroll
    for (int j = 0; j < 4; ++j) acc[i][j] = (f32x4){0.f,0.f,0.f,0.f};

  const short* gA0 = A + (size_t)(tM + (tid>>2))*KP + (tid&3)*8;
  const short* gA1 = A + (size_t)(tM + 64 + (tid>>2))*KP + (tid&3)*8;
  const short* gB0 = B + (size_t)(tN + (tid>>2))*KP + (tid&3)*8;
  const short* gB1 = B + (size_t)(tN + 64 + (tid>>2))*KP + (tid&3)*8;
  short* lA0 = Asl + wave*512;
  short* lA1 = Asl + 2048 + wave*512;
  short* lB0 = Bsl + wave*512;
  short* lB1 = Bsl + 2048 + wave*512;

  for (int k0 = 0; k0 < KP; k0 += KT){
    __syncthreads();
    gload_lds16(gA0 + k0, lA0);
    gload_lds16(gA1 + k0, lA1);
    gload_lds16(gB0 + k0, lB0);
    gload_lds16(gB1 + k0, lB1);
    __syncthreads();

    bf16x8 af[4], bfr[4];
    #pragma unroll
    for (int mi = 0; mi < 4; ++mi)
      af[mi] = *(const bf16x8*)(Asl + (wr*64 + mi*16 + l15)*32 + l4*8);
    #pragma unroll
    for (int nj = 0; nj < 4; ++nj)
      bfr[nj] = *(const bf16x8*)(Bsl + (wc*64 + nj*16 + l15)*32 + l4*8);
    #pragma unroll
    for (int mi = 0; mi < 4; ++mi)
      #pragma unroll
      for (int nj = 0; nj < 4; ++nj)
        acc[mi][nj] = __builtin_amdgcn_mfma_f32_16x16x32_bf16(af[mi], bfr[nj], acc[mi][nj], 0, 0, 0);
  }

  #pragma unroll
  for (int mi = 0; mi < 4; ++mi){
    #pragma unroll
    for (int r = 0; r < 4; ++r){
      int gr = tM + wr*64 + mi*16 + l4*4 + r;
      if (gr >= M) continue;
      #pragma unroll
      for (int nj = 0; nj < 4; ++nj){
        int gc = tN + wc*64 + nj*16 + l15;
        if (gc >= Nd) continue;
        float v = acc[mi][nj][r];
        if (bias) v += bias[gc];
        if (Cf) Cf[(size_t)gr*Nd + gc] = v;
        else    Cb[(size_t)gr*ldcb + gc] = __float2bfloat16(v);
      }
    }
  }
}

// ===================== MFMA bf16 GEMM 256x256 tile (adj): 512 thr, 8 waves 2x4 =====================
__global__ __launch_bounds__(512)
void k_gemm_abt_mfma256(const short* __restrict__ A, const short* __restrict__ B,
                        float* __restrict__ Cf, int M, int Nd, int KP){
  __shared__ __align__(16) short Asl[256*32];
  __shared__ __align__(16) short Bsl[256*32];
  // bijective XCD swizzle over nwg = gridDim.x*gridDim.y (1600: q=200,r=0)
  int gx = gridDim.x;
  int nwg = gx * gridDim.y;
  int bid = blockIdx.y*gx + blockIdx.x;
  int q = nwg >> 3, r = nwg & 7;
  int xcd = bid & 7, o = bid >> 3;
  int nb = (xcd < r ? xcd*(q+1) : r*(q+1) + (xcd - r)*q) + o;
  int bx = nb % gx, by = nb / gx;

  int tid = threadIdx.x;
  int lane = tid & 63, wave = tid >> 6;      // 8 waves
  int wr = wave >> 2, wc = wave & 3;         // 2 x 4 wave grid; per-wave 128x64
  int l15 = lane & 15, l4 = lane >> 4;
  int tM = by * 256, tN = bx * 256;

  f32x4 acc[8][4];
  #pragma unroll
  for (int i = 0; i < 8; ++i)
    #pragma unroll
    for (int j = 0; j < 4; ++j) acc[i][j] = (f32x4){0.f,0.f,0.f,0.f};

  // staging: wave w covers rows w*16..w*16+15 (call 0) / +128 (call 1); lane l: row +(l>>2), 16B chunk (l&3)
  int srow = wave*16 + (lane >> 2), q2 = lane & 3;
  const short* gA0 = A + (size_t)(tM + srow)*KP + q2*8;
  const short* gA1 = A + (size_t)(tM + 128 + srow)*KP + q2*8;
  const short* gB0 = B + (size_t)(tN + srow)*KP + q2*8;
  const short* gB1 = B + (size_t)(tN + 128 + srow)*KP + q2*8;
  short* lA0 = Asl + wave*512;           // rows 0-127 region: 8 waves x 1KB
  short* lA1 = Asl + 4096 + wave*512;    // rows 128-255
  short* lB0 = Bsl + wave*512;
  short* lB1 = Bsl + 4096 + wave*512;

  for (int k0 = 0; k0 < KP; k0 += KT){
    __syncthreads();
    gload_lds16(gA0 + k0, lA0);
    gload_lds16(gA1 + k0, lA1);
    gload_lds16(gB0 + k0, lB0);
    gload_lds16(gB1 + k0, lB1);
    __syncthreads();

    bf16x8 af[8], bfr[4];
    #pragma unroll
    for (int mi = 0; mi < 8; ++mi)
      af[mi] = *(const bf16x8*)(Asl + (wr*128 + mi*16 + l15)*32 + l4*8);
    #pragma unroll
    for (int nj = 0; nj < 4; ++nj)
      bfr[nj] = *(const bf16x8*)(Bsl + (wc*64 + nj*16 + l15)*32 + l4*8);
    #pragma unroll
    for (int mi = 0; mi < 8; ++mi)
      #pragma unroll
      for (int nj = 0; nj < 4; ++nj)
        acc[mi][nj] = __builtin_amdgcn_mfma_f32_16x16x32_bf16(af[mi], bfr[nj], acc[mi][nj], 0, 0, 0);
  }

  #pragma unroll
  for (int mi = 0; mi < 8; ++mi){
    #pragma unroll
    for (int r = 0; r < 4; ++r){
      int gr = tM + wr*128 + mi*16 + l4*4 + r;
      if (gr >= M) continue;
      #pragma unroll
      for (int nj = 0; nj < 4; ++nj){
        int gc = tN + wc*64 + nj*16 + l15;
        if (gc < Nd) Cf[(size_t)gr*Nd + gc] = acc[mi][nj][r];
      }
    }
  }
}

// merged split-K pooling GEMMs: z/8 selects {0: s^T xb, 1: s^T a_s, 2: s^T s}
__global__ __launch_bounds__(256)
void k_pool_sk(const short* __restrict__ st, const short* __restrict__ xbt,
               const short* __restrict__ a_st,
               float* __restrict__ out_pool, float* __restrict__ P, float* __restrict__ ssm,
               int K, int Hd, int KL, int kChunk){
  __shared__ __align__(16) short Asl[128*32];
  __shared__ __align__(16) short Bsl[128*32];
  int sel = blockIdx.z >> 3;
  int chunk = blockIdx.z & 7;
  const short* B = (sel == 0) ? xbt : (sel == 1) ? a_st : st;
  float* C = (sel == 0) ? out_pool : (sel == 1) ? P : ssm;
  int Nd = (sel == 0) ? Hd : K;
  if ((int)blockIdx.x * NT >= ((sel == 0) ? Hd : 512)) return;
  int tid = threadIdx.x;
  int lane = tid & 63, wave = tid >> 6;
  int wr = wave >> 1, wc = wave & 1;
  int l15 = lane & 15, l4 = lane >> 4;
  int tM = blockIdx.y * MT, tN = blockIdx.x * NT;
  int kBeg = chunk * kChunk;
  int kEnd = min(KL, kBeg + kChunk);

  f32x4 acc[4][4];
  #pragma unroll
  for (int i = 0; i < 4; ++i)
    #pragma unroll
    for (int j = 0; j < 4; ++j) acc[i][j] = (f32x4){0.f,0.f,0.f,0.f};

  const short* gA0 = st + (size_t)(tM + (tid>>2))*KL + (tid&3)*8;
  const short* gA1 = st + (size_t)(tM + 64 + (tid>>2))*KL + (tid&3)*8;
  const short* gB0 = B + (size_t)(tN + (tid>>2))*KL + (tid&3)*8;
  const short* gB1 = B + (size_t)(tN + 64 + (tid>>2))*KL + (tid&3)*8;
  short* lA0 = Asl + wave*512;
  short* lA1 = Asl + 2048 + wave*512;
  short* lB0 = Bsl + wave*512;
  short* lB1 = Bsl + 2048 + wave*512;

  for (int k0 = kBeg; k0 < kEnd; k0 += KT){
    __syncthreads();
    gload_lds16(gA0 + k0, lA0);
    gload_lds16(gA1 + k0, lA1);
    gload_lds16(gB0 + k0, lB0);
    gload_lds16(gB1 + k0, lB1);
    __syncthreads();

    bf16x8 af[4], bfr[4];
    #pragma unroll
    for (int mi = 0; mi < 4; ++mi)
      af[mi] = *(const bf16x8*)(Asl + (wr*64 + mi*16 + l15)*32 + l4*8);
    #pragma unroll
    for (int nj = 0; nj < 4; ++nj)
      bfr[nj] = *(const bf16x8*)(Bsl + (wc*64 + nj*16 + l15)*32 + l4*8);
    #pragma unroll
    for (int mi = 0; mi < 4; ++mi)
      #pragma unroll
      for (int nj = 0; nj < 4; ++nj)
        acc[mi][nj] = __builtin_amdgcn_mfma_f32_16x16x32_bf16(af[mi], bfr[nj], acc[mi][nj], 0, 0, 0);
  }

  #pragma unroll
  for (int mi = 0; mi < 4; ++mi){
    #pragma unroll
    for (int r = 0; r < 4; ++r){
      int gr = tM + wr*64 + mi*16 + l4*4 + r;
      if (gr >= K) continue;
      #pragma unroll
      for (int nj = 0; nj < 4; ++nj){
        int gc = tN + wc*64 + nj*16 + l15;
        if (gc >= Nd) continue;
        atomicAdd(&C[(size_t)gr*Nd + gc], acc[mi][nj][r]);
      }
    }
  }
}

// ===================== softmax + reductions =====================

__global__ __launch_bounds__(256)
void k_softmax(float* __restrict__ s, __hip_bfloat16* __restrict__ sb,
               const int* __restrict__ outdeg,
               float* __restrict__ scalars, int N, int K, int KP){
  int wid = threadIdx.x >> 6, lane = threadIdx.x & 63;
  int row = blockIdx.x*4 + wid;
  if (row >= N) return;
  float* sr = s + (size_t)row*K;
  __hip_bfloat16* sbr = sb + (size_t)row*KP;
  float v[8];
  float m = -INFINITY;
  #pragma unroll
  for (int i = 0; i < 8; ++i){
    int k = lane + i*64;
    v[i] = (k < K) ? sr[k] : -INFINITY;
    m = fmaxf(m, v[i]);
  }
  for (int off = 32; off; off >>= 1) m = fmaxf(m, __shfl_xor(m, off));
  float sum = 0.f;
  #pragma unroll
  for (int i = 0; i < 8; ++i){
    int k = lane + i*64;
    if (k < K){ v[i] = expf(v[i] - m); sum += v[i]; } else v[i] = 0.f;
  }
  for (int off = 32; off; off >>= 1) sum += __shfl_xor(sum, off);
  float inv = 1.f / sum;
  float ssq = 0.f;
  #pragma unroll
  for (int i = 0; i < 8; ++i){
    int k = lane + i*64;
    if (k < K){
      float p = v[i]*inv;
      sr[k] = p;
      sbr[k] = __float2bfloat16(p);
      ssq += p*p;
    }
  }
  for (int off = 32; off; off >>= 1) ssq += __shfl_xor(ssq, off);
  if (lane == 0) atomicAdd(&scalars[1], (float)outdeg[row] * ssq);
}

__global__ void k_stats1(const float* __restrict__ P, const float* __restrict__ ssm,
                         float* __restrict__ scalars, int K){
  float tr = 0.f, sq = 0.f;
  int n = K*K;
  for (int idx = blockIdx.x*blockDim.x + threadIdx.x; idx < n; idx += gridDim.x*blockDim.x){
    float v = ssm[idx]; sq += v*v;
    int i = idx / K, j = idx - i*K;
    if (i == j) tr += P[idx];
  }
  for (int off = 32; off; off >>= 1){
    tr += __shfl_xor(tr, off);
    sq += __shfl_xor(sq, off);
  }
  if ((threadIdx.x & 63) == 0){
    if (tr != 0.f) atomicAdd(&scalars[0], tr);
    atomicAdd(&scalars[2], sq);
  }
}

__global__ __launch_bounds__(256)
void k_rowsum_d(const float* __restrict__ P, float* __restrict__ dvec, int K){
  int wid = threadIdx.x >> 6, lane = threadIdx.x & 63;
  int row = blockIdx.x*4 + wid;
  if (row >= K) return;
  const float* pr = P + (size_t)row*K;
  float rs = 0.f;
  for (int j = lane; j < K; j += 64) if (j != row) rs += pr[j];
  for (int off = 32; off; off >>= 1) rs += __shfl_xor(rs, off);
  if (lane == 0) dvec[row] = sqrtf(rs) + EPSF;
}

__global__ void k_stats2(float* __restrict__ P, const float* __restrict__ ssm,
                         const float* __restrict__ dvec,
                         const float* __restrict__ scalars, float* __restrict__ out3, int K){
  float inv = 1.f / (sqrtf(scalars[2]) + EPSF);
  float isk = rsqrtf((float)K);
  float a = 0.f;
  int n = K*K;
  for (int idx = blockIdx.x*blockDim.x + threadIdx.x; idx < n; idx += gridDim.x*blockDim.x){
    int i = idx / K, j = idx - i*K;
    float v = ssm[idx]*inv - ((i == j) ? isk : 0.f);
    a += v*v;
    float pv = P[idx];
    P[idx] = (i == j) ? 0.f : pv / (dvec[i]*dvec[j]);
  }
  for (int off = 32; off; off >>= 1) a += __shfl_xor(a, off);
  if ((threadIdx.x & 63) == 0) atomicAdd(out3, a);
}

__global__ void k_finalize(const float* __restrict__ scalars, float* __restrict__ out2){
  if (threadIdx.x == 0){
    out2[0] = -(scalars[0] / (scalars[1] + EPSF));
    out2[1] = sqrtf(scalars[3]);
  }
}

// ===================== host-side orchestration =====================

extern "C" void kernel_launch(void* const* d_in, const int* in_sizes, int n_in,
                              void* d_out, int out_size, void* d_ws, size_t ws_size,
                              hipStream_t stream) {
  const float* nodes = (const float*)d_in[0];
  const int*   edges = (const int*)d_in[1];
  const float* W1 = (const float*)d_in[3];  const float* b1 = (const float*)d_in[4];
  const float* W2 = (const float*)d_in[5];  const float* b2 = (const float*)d_in[6];
  const float* pW = (const float*)d_in[7];  const float* pB = (const float*)d_in[8];
  const float* W3 = (const float*)d_in[9];  const float* b3 = (const float*)d_in[10];
  const float* W4 = (const float*)d_in[11]; const float* b4 = (const float*)d_in[12];
  const float* W5 = (const float*)d_in[13]; const float* b5 = (const float*)d_in[14];

  const int H = 128, F = 128, N = 10000, E = 320000, K = 500;
  const int KP = 512;
  const int NP = 10016;
  const int MP = 80*128;   // 10240: covers 40x256 adj tiles AND 80x128 tiles
  (void)n_in; (void)out_size; (void)in_sizes;

  float* out_x   = (float*)d_out;
  float* out_adj = out_x + (size_t)N*F;
  float* out_ls  = out_adj + (size_t)N*N;

  char* ws = (char*)d_ws;
  size_t off = 0;
  auto alloc = [&](size_t bytes) -> void* {
    off = (off + 255) & ~(size_t)255;
    void* p = ws + off;
    off += bytes;
    return p;
  };
  int*   deg2       = (int*)alloc((size_t)2*N*4);
  int*   indeg      = deg2;
  int*   outdeg     = deg2 + N;
  float* zf         = (float*)alloc(((size_t)K*H + 2*(size_t)K*K + 64)*4);
  float* out_pool   = zf;
  float* P          = zf + (size_t)K*H;
  float* ssm        = P + (size_t)K*K;
  float* scalars    = ssm + (size_t)K*K;
  __hip_bfloat16* s_b = (__hip_bfloat16*)alloc((size_t)MP*KP*2);
  __hip_bfloat16* u_b = (__hip_bfloat16*)alloc((size_t)MP*KP*2);
  int*   rowptr_in  = (int*)alloc((size_t)(N+1)*4);
  int*   rowptr_out = (int*)alloc((size_t)(N+1)*4);
  int*   cur_in     = (int*)alloc((size_t)N*4);
  int*   cur_out    = (int*)alloc((size_t)N*4);
  int*   csr_src    = (int*)alloc((size_t)E*4);
  int*   csr_dst    = (int*)alloc((size_t)E*4);
  float* dinv       = (float*)alloc((size_t)N*4);
  __hip_bfloat16* h_b  = (__hip_bfloat16*)alloc((size_t)N*H*2 + 32768);
  __hip_bfloat16* nodes_b = (__hip_bfloat16*)alloc((size_t)MP*H*2);
  __hip_bfloat16* xa_b = (__hip_bfloat16*)alloc((size_t)MP*H*2);
  __hip_bfloat16* xb_b = (__hip_bfloat16*)alloc((size_t)MP*H*2);
  float* s          = (float*)alloc((size_t)N*K*4);
  float* a_s        = (float*)alloc((size_t)N*K*4);
  float* dvec       = (float*)alloc((size_t)K*4);
  __hip_bfloat16* Pt_b = (__hip_bfloat16*)alloc((size_t)KP*KP*2);
  __hip_bfloat16* st_b = (__hip_bfloat16*)alloc((size_t)KP*NP*2);
  __hip_bfloat16* a_st = (__hip_bfloat16*)alloc((size_t)KP*NP*2);
  __hip_bfloat16* xbt  = (__hip_bfloat16*)alloc((size_t)H*NP*2);
  __hip_bfloat16* opT  = (__hip_bfloat16*)alloc((size_t)H*KP*2);
  __hip_bfloat16* W1t  = (__hip_bfloat16*)alloc((size_t)H*F*2);
  __hip_bfloat16* W2t  = (__hip_bfloat16*)alloc((size_t)H*H*2);
  __hip_bfloat16* W3t  = (__hip_bfloat16*)alloc((size_t)H*H*2);
  __hip_bfloat16* W4t  = (__hip_bfloat16*)alloc((size_t)H*H*2);
  __hip_bfloat16* W5t  = (__hip_bfloat16*)alloc((size_t)F*H*2);
  __hip_bfloat16* pWt  = (__hip_bfloat16*)alloc((size_t)KP*H*2);
  (void)ws_size;

  hipMemsetAsync(deg2, 0, (size_t)2*N*4, stream);
  hipMemsetAsync(zf,   0, ((size_t)K*H + 2*(size_t)K*K + 64)*4, stream);
  k_zero_pads<<<512, 256, 0, stream>>>(s_b, u_b, N, K, KP, MP);

  // --- graph structure ---
  int eb = (E + 255)/256;
  k_count_deg<<<eb, 256, 0, stream>>>(edges, E, indeg, outdeg);
  k_scan_batch<<<2, 256, 0, stream>>>(indeg, outdeg, rowptr_in, rowptr_out,
                                      cur_in, cur_out, dinv, N);
  k_fill_csr<<<eb, 256, 0, stream>>>(edges, E, cur_in, cur_out, csr_src, csr_dst);

  // --- weight packs ---
  {
    TPar p0 = { W1, W1t, F, H, H, F };
    TPar p1 = { W2, W2t, H, H, H, H };
    TPar p2 = { W3, W3t, H, H, H, H };
    TPar p3 = { W4, W4t, H, H, H, H };
    TPar p4 = { W5, W5t, H, F, F, H };
    TPar p5 = { pW, pWt, H, K, KP, H };
    dim3 g(16, 4, 6);
    k_transpose_batch6<<<g, 256, 0, stream>>>(p0, p1, p2, p3, p4, p5);
  }
  k_pack_bf16pad<<<1024, 256, 0, stream>>>(nodes, nodes_b, N, F, F);

  auto mfma = [&](const __hip_bfloat16* A, const __hip_bfloat16* B, const float* bias,
                  float* Cf, __hip_bfloat16* Cb, int M, int Nd, int Kp, int ldcb){
    dim3 g((Nd + NT - 1)/NT, (M + MT - 1)/MT);
    k_gemm_abt_mfma<<<g, 256, 0, stream>>>((const short*)A, (const short*)B, bias,
                                           Cf, Cb, M, Nd, Kp, ldcb);
  };

  // --- conv1, conv2 ---
  mfma(nodes_b, W1t, nullptr, nullptr, h_b, N, H, F, H);
  k_gcn_agg_v2<<<(N+3)/4, 128, 0, stream>>>(h_b, dinv, rowptr_in, csr_src, b1, nullptr, xa_b, H/4, N, 1);
  mfma(xa_b, W2t, nullptr, nullptr, h_b, N, H, H, H);
  k_gcn_agg_v2<<<(N+3)/4, 128, 0, stream>>>(h_b, dinv, rowptr_in, csr_src, b2, nullptr, xb_b, H/4, N, 1);

  // --- pooling ---
  mfma(xb_b, pWt, pB, s, nullptr, N, K, H, 0);
  k_softmax<<<(N+3)/4, 256, 0, stream>>>(s, s_b, outdeg, scalars, N, K, KP);
  k_as_agg_b4<<<N, 128, 0, stream>>>(s_b, rowptr_out, csr_dst, a_s, K, K/4, KP/4);
  { dim3 g(KP/32, NP/32, 3); k_transpose_batch3<<<g, 256, 0, stream>>>(s, st_b, a_s, a_st,
                                                                       xb_b, xbt, N, K, KP, H, NP); }
  const int kChunk = 1280;
  { dim3 g(4, 4, 24); k_pool_sk<<<g, 256, 0, stream>>>((const short*)st_b, (const short*)xbt,
                                                       (const short*)a_st,
                                                       out_pool, P, ssm, K, H, NP, kChunk); }
  k_stats1<<<128, 256, 0, stream>>>(P, ssm, scalars, K);
  k_rowsum_d<<<(K+3)/4, 256, 0, stream>>>(P, dvec, K);
  k_stats2<<<128, 256, 0, stream>>>(P, ssm, dvec, scalars, &scalars[3], K);
  k_finalize<<<1, 64, 0, stream>>>(scalars, out_ls);

  // --- reconstruction ---
  { dim3 g(16, 16, 2); k_transpose_ptop<<<g, 256, 0, stream>>>(P, Pt_b, out_pool, opT, K, KP, H); }
  mfma(s_b, Pt_b, nullptr, nullptr, u_b, N, K, KP, KP);
  {
    dim3 g(40, 40);   // 256x256 tiles over 10240x10240 (guards clip to 10000)
    k_gemm_abt_mfma256<<<g, 512, 0, stream>>>((const short*)u_b, (const short*)s_b,
                                              out_adj, N, N, KP);
  }
  mfma(s_b, opT, nullptr, nullptr, xa_b, N, H, KP, H);

  // --- conv3, conv4, conv5 ---
  mfma(xa_b, W3t, nullptr, nullptr, h_b, N, H, H, H);
  k_gcn_agg_v2<<<(N+3)/4, 128, 0, stream>>>(h_b, dinv, rowptr_in, csr_src, b3, nullptr, xb_b, H/4, N, 1);
  mfma(xb_b, W4t, nullptr, nullptr, h_b, N, H, H, H);
  k_gcn_agg_v2<<<(N+3)/4, 128, 0, stream>>>(h_b, dinv, rowptr_in, csr_src, b4, nullptr, xa_b, H/4, N, 1);
  mfma(xa_b, W5t, nullptr, nullptr, h_b, N, F, H, F);
  k_gcn_agg_v2<<<(N+3)/4, 128, 0, stream>>>(h_b, dinv, rowptr_in, csr_src, b5, out_x, nullptr, F/4, N, 0);
}